// Round 14
// baseline (100.965 us; speedup 1.0000x reference)
//
#include <hip/hip_runtime.h>

// IGD metric kernel for MI355X (gfx950) — R14: barrier-free K-loop (whole split LDS-resident).
// d2(i,j) = pfsq[i] + xsq[j] + dot(e4m3(-2*pf_i), e4m3(x_j)); norms in fp32 from DECODED fp8 ->
// d2 = exact sq-distance of rounded points. MX-scaled 32x32x64 MFMA, unity scales.
// R13 post-mortem: clean 6-wave TLP test NULL. Surviving invariants: MFMA busy == demand;
// wall = C(~27us) + MFMA_demand SERIAL; C invariant under delivery/ILP/VALU/TLP. Signature of
// phase LOCKSTEP: per-chunk __syncthreads + vmcnt drain re-syncs all waves every few hundred
// cycles -> stall/MFMA/VALU phases never overlap across waves; C = drain x nchunks.
// R14: NSPLIT=24 -> split slice <= 45 KB fp8; stage it ONCE (async DMA), ONE barrier, then a
// barrier-free 21/22-unit K-loop from LDS. 47.9 KB LDS -> 3 blocks/CU; grid (64,24)=1536 -> two
// staggered generations (extra de-phasing). Per-wave shape == R11 (64 rows, 2 MFMA/unit).
// Harness poison fill of ws (~42 us @6.5TB/s) is a fixed floor inside the timed window.

typedef float f32x16 __attribute__((ext_vector_type(16)));
typedef int i32x8 __attribute__((ext_vector_type(8)));
typedef unsigned long long u64;

#define DIM 64
#define NSPLIT 24
#define UNITB 2048            // bytes per 32-col unit: 4 qfrags x 64 lanes x 8 B
#define MAXU 22               // max units per split (512 = 8*22 + 16*21)
#define MTILE 256             // rows per block (4 waves x 64 rows)

union BFrag { u64 q[4]; i32x8 v; };

// async global->LDS DMA, 16 B/lane (global_load_lds_dwordx4) and 4 B/lane
__device__ __forceinline__ void g2lds16(const void* g, void* l) {
    __builtin_amdgcn_global_load_lds(
        (const __attribute__((address_space(1))) unsigned int*)g,
        (__attribute__((address_space(3))) unsigned int*)l, 16, 0, 0);
}
__device__ __forceinline__ void g2lds4(const void* g, void* l) {
    __builtin_amdgcn_global_load_lds(
        (const __attribute__((address_space(1))) unsigned int*)g,
        (__attribute__((address_space(3))) unsigned int*)l, 4, 0, 0);
}

// ---- manual OCP e4m3fn encode (RNE, denormals, saturate) / decode ----
__device__ inline unsigned char enc_e4m3(float f) {
    unsigned int u = __float_as_uint(f);
    unsigned int s = (u >> 24) & 0x80u;
    unsigned int a = u & 0x7FFFFFFFu;
    if ((a >> 23) >= 121u) {                       // |f| >= 2^-6 : normal range
        unsigned int lsb = (a >> 20) & 1u;
        unsigned int r = a + 0x7FFFFu + lsb;       // RNE on 3-bit mantissa
        int e = (int)(r >> 23) - 120;              // rebias 127 -> 7
        unsigned int m = (r >> 20) & 7u;
        if (e > 15 || (e == 15 && m == 7u)) return (unsigned char)(s | 0x7Eu);  // sat 448
        return (unsigned char)(s | ((unsigned)e << 3) | m);
    }
    int m = (int)rintf(__uint_as_float(a) * 512.0f);   // denormal: multiples of 2^-9
    return (unsigned char)(s | (unsigned)m);
}

__device__ inline float dec_e4m3(unsigned char b) {
    int e = (b >> 3) & 15, m = b & 7;
    float v = e ? __uint_as_float((unsigned)((e + 120) << 23) | ((unsigned)m << 20))
                : (float)m * 0.001953125f;         // 2^-9
    return (b & 0x80) ? -v : v;
}

// ---------------- pack ----------------
// Bp layout (32x32x64 B-operand): lane L = h*32 + c31 holds col = u*32+c31, k = h*32 + 0..31:
//   Bp[u*2048 + q*512 + L*8 + b] = e4m3(x[col][h*32 + q*8 + b]).
// xsq[col] = exact fp32 sum of squares of decoded values.
// pf -> Ab row-major fp8(-2*pf) (A-operand = contiguous 32 B per lane); pfsq = 0.25*sum(dec^2).
__global__ void pack_kernel(const float* __restrict__ x, const float* __restrict__ pf,
                            unsigned char* __restrict__ Bp, unsigned char* __restrict__ Ab,
                            float* __restrict__ xsq, float* __restrict__ pfsq,
                            float* __restrict__ out, int N, int M) {
    int gid = blockIdx.x * blockDim.x + threadIdx.x;
    if (gid == 0) out[0] = 0.f;
    if (gid < N * 4) {
        int col = gid >> 2, t = gid & 3;
        const float* s = x + (size_t)col * DIM + t * 16;
        float partial = 0.f;
        u64 w[2] = {0, 0};
#pragma unroll
        for (int h = 0; h < 2; ++h) {
            float4 v0 = *(const float4*)(s + h * 8);
            float4 v1 = *(const float4*)(s + h * 8 + 4);
            float f[8] = {v0.x, v0.y, v0.z, v0.w, v1.x, v1.y, v1.z, v1.w};
#pragma unroll
            for (int j = 0; j < 8; ++j) {
                unsigned char b = enc_e4m3(f[j]);
                w[h] |= (u64)b << (8 * j);
                float d = dec_e4m3(b);
                partial += d * d;
            }
        }
        int u = col >> 5, c31 = col & 31;
        unsigned char* ub = Bp + (size_t)u * UNITB;
        int h = t >> 1;
#pragma unroll
        for (int ss = 0; ss < 2; ++ss) {
            int q = (t & 1) * 2 + ss;
            *(u64*)(ub + (size_t)q * 512 + (size_t)(h * 32 + c31) * 8) = w[ss];
        }
        partial += __shfl_xor(partial, 1);
        partial += __shfl_xor(partial, 2);
        if (t == 0) xsq[col] = partial;
    } else {
        int g = gid - N * 4;
        int row = g >> 2, q = g & 3;
        if (row >= M) return;
        const float* s = pf + (size_t)row * DIM + q * 16;
        float partial = 0.f;
        u64 w[2] = {0, 0};
#pragma unroll
        for (int h = 0; h < 2; ++h) {
            float4 v0 = *(const float4*)(s + h * 8);
            float4 v1 = *(const float4*)(s + h * 8 + 4);
            float f[8] = {v0.x, v0.y, v0.z, v0.w, v1.x, v1.y, v1.z, v1.w};
#pragma unroll
            for (int j = 0; j < 8; ++j) {
                unsigned char b = enc_e4m3(f[j] * -2.f);
                w[h] |= (u64)b << (8 * j);
                float d = dec_e4m3(b);
                partial += d * d;
            }
        }
        *(u64*)(Ab + (size_t)row * DIM + q * 16)     = w[0];
        *(u64*)(Ab + (size_t)row * DIM + q * 16 + 8) = w[1];
        partial += __shfl_xor(partial, 1);
        partial += __shfl_xor(partial, 2);
        if (q == 0) pfsq[row] = partial * 0.25f;
    }
}

// ---------------- main: whole-split LDS, ONE barrier, barrier-free K-loop ----------------
__global__ __launch_bounds__(256, 3)
void igd_main(const unsigned char* __restrict__ A, const unsigned char* __restrict__ Bp,
              const float* __restrict__ xsq, float* __restrict__ partial, int N) {
    __shared__ unsigned char ldsB[MAXU * UNITB];  // 45056 B
    __shared__ float ldsX[MAXU * 32];             // 2816 B
    const int tid = threadIdx.x;
    const int mTile  = blockIdx.x;
    const int nsplit = blockIdx.y;
    const int lane = tid & 63;
    const int wave = tid >> 6;
    const int half = lane >> 5;
    const int l31  = lane & 31;
    const int rowBase = mTile * MTILE + wave * 64;

    // ragged split over 32-col units: 512 = 8 splits of 22 + 16 splits of 21
    const int utotal = N / 32;
    const int ubase  = utotal / NSPLIT;
    const int urem   = utotal % NSPLIT;
    const int ustart = nsplit * ubase + (nsplit < urem ? nsplit : urem);
    const int ucount = ubase + (nsplit < urem ? 1 : 0);

    const unsigned char* gB = Bp + (size_t)ustart * UNITB;
    const float* gX = xsq + ustart * 32;

    // Stage the WHOLE split slice once: async DMA, no VGPR round-trip.
    {
        int bytes = ucount * UNITB;
#pragma unroll
        for (int i = 0; i < 11; ++i) {
            int off = i * 4096 + tid * 16;
            if (off < bytes) g2lds16(gB + off, &ldsB[off]);
        }
        int xcnt = ucount * 32;
#pragma unroll
        for (int j = 0; j < 3; ++j) {
            int idx = j * 256 + tid;
            if (idx < xcnt) g2lds4(gX + idx, &ldsX[idx]);
        }
    }

    // Persistent A operands (overlaps the DMA): lane holds A[row=l31+32g][k=half*32..+31]
    BFrag a[2];
#pragma unroll
    for (int g = 0; g < 2; ++g) {
        const unsigned char* ap = A + (size_t)(rowBase + 32 * g + l31) * DIM + half * 32;
#pragma unroll
        for (int qq = 0; qq < 4; ++qq)
            a[g].q[qq] = *(const u64*)(ap + qq * 8);
    }

    f32x16 zero, m0, m1;
#pragma unroll
    for (int r = 0; r < 16; ++r) { zero[r] = 0.f; m0[r] = 1e30f; m1[r] = 1e30f; }

    __syncthreads();   // the ONLY barrier: drains DMA, then the K-loop is barrier-free

#define LOADF(rr, u)                                                           \
    {                                                                          \
        const unsigned char* p = &ldsB[0] + lane * 8 + (u) * UNITB;            \
        rr.q[0] = *(const u64*)(p);                                            \
        rr.q[1] = *(const u64*)(p + 512);                                      \
        rr.q[2] = *(const u64*)(p + 1024);                                     \
        rr.q[3] = *(const u64*)(p + 1536);                                     \
    }

    // Unity E8M0 scales (0x7F = 2^0): bit-identical to non-scaled fp8 accumulation.
#define STEP(bfrag, xq)                                                        \
    {                                                                          \
        f32x16 acc0 = __builtin_amdgcn_mfma_scale_f32_32x32x64_f8f6f4(         \
            a[0].v, bfrag.v, zero, 0, 0, 0, 0x7F7F7F7F, 0, 0x7F7F7F7F);        \
        f32x16 acc1 = __builtin_amdgcn_mfma_scale_f32_32x32x64_f8f6f4(         \
            a[1].v, bfrag.v, zero, 0, 0, 0, 0x7F7F7F7F, 0, 0x7F7F7F7F);        \
        _Pragma("unroll")                                                      \
        for (int r = 0; r < 16; ++r) {                                         \
            m0[r] = fminf(m0[r], acc0[r] + (xq));                              \
            m1[r] = fminf(m1[r], acc1[r] + (xq));                              \
        }                                                                      \
    }

    {
        BFrag b0, b1;
        LOADF(b0, 0);
        for (int u = 0; u < ucount; u += 2) {
            if (u + 1 < ucount) LOADF(b1, u + 1);
            STEP(b0, ldsX[u * 32 + l31]);
            if (u + 2 < ucount) LOADF(b0, u + 2);
            if (u + 1 < ucount) STEP(b1, ldsX[(u + 1) * 32 + l31]);
        }
    }
#undef LOADF
#undef STEP

    // cross-lane min over the 32 lanes sharing a row
#pragma unroll
    for (int mask = 1; mask <= 16; mask <<= 1) {
#pragma unroll
        for (int r = 0; r < 16; ++r) {
            m0[r] = fminf(m0[r], __shfl_xor(m0[r], mask));
            m1[r] = fminf(m1[r], __shfl_xor(m1[r], mask));
        }
    }
    if (l31 == 0) {
        // C/D layout (shape-determined, FMT-independent): row = (r&3)+8*(r>>2)+4*half
#pragma unroll
        for (int r = 0; r < 16; ++r) {
            int row0 = rowBase + (r & 3) + 8 * (r >> 2) + 4 * half;
            partial[(size_t)row0 * NSPLIT + nsplit] = m0[r];
            partial[(size_t)(row0 + 32) * NSPLIT + nsplit] = m1[r];
        }
    }
}

// ---------------- reduce: min over splits, add pfsq, sqrt, mean ----------------
__global__ void reduce_kernel(const float* __restrict__ partial, const float* __restrict__ pfsq,
                              float* __restrict__ out, int M, float invM) {
    int row = blockIdx.x * blockDim.x + threadIdx.x;
    float v = 0.f;
    if (row < M) {
        const float* p = partial + (size_t)row * NSPLIT;
        float mn = 3.4e38f;
#pragma unroll 8
        for (int s = 0; s < NSPLIT; ++s) mn = fminf(mn, p[s]);
        float d2 = mn + pfsq[row];
        v = sqrtf(fmaxf(d2, 0.f)) * invM;
    }
#pragma unroll
    for (int m = 1; m < 64; m <<= 1) v += __shfl_xor(v, m);
    __shared__ float wsum[4];
    int lane = threadIdx.x & 63, w = threadIdx.x >> 6;
    if (lane == 0) wsum[w] = v;
    __syncthreads();
    if (threadIdx.x == 0) atomicAdd(out, wsum[0] + wsum[1] + wsum[2] + wsum[3]);
}

extern "C" void kernel_launch(void* const* d_in, const int* in_sizes, int n_in,
                              void* d_out, int out_size, void* d_ws, size_t ws_size,
                              hipStream_t stream) {
    const float* x  = (const float*)d_in[0];   // [N, 64]
    const float* pf = (const float*)d_in[1];   // [M, 64]
    const int N = in_sizes[0] / DIM;
    const int M = in_sizes[1] / DIM;

    char* ws = (char*)d_ws;
    unsigned char* Bp = (unsigned char*)ws;                        // N*64 bytes (packed fp8)
    unsigned char* Ab = (unsigned char*)(ws + (size_t)N * DIM);    // M*64 bytes
    float* xsq  = (float*)(ws + (size_t)(N + M) * DIM);            // N floats
    float* pfsq = xsq + N;                                         // M floats
    float* part = pfsq + M;                                        // M*NSPLIT floats

    int packThreads = (N + M) * 4;
    pack_kernel<<<dim3((packThreads + 255) / 256), 256, 0, stream>>>(
        x, pf, Bp, Ab, xsq, pfsq, (float*)d_out, N, M);
    igd_main<<<dim3(M / MTILE, NSPLIT), 256, 0, stream>>>(Ab, Bp, xsq, part, N);
    reduce_kernel<<<dim3((M + 255) / 256), 256, 0, stream>>>(part, pfsq, (float*)d_out, M, 1.f / (float)M);
}

// Round 15
// 87.190 us; speedup vs baseline: 1.1580x; 1.1580x over previous
//
#include <hip/hip_runtime.h>

// IGD metric kernel for MI355X (gfx950) — R15: R11 igd_main (best measured) + HW fp8 cvt pack.
// d2(i,j) = pfsq[i] + xsq[j] + dot(e4m3(-2*pf_i), e4m3(x_j)); norms in fp32 from the HW-DECODED
// fp8 bytes -> d2 = exact sq-distance of rounded points regardless of HW rounding mode.
// R14 post-mortem: barrier-free whole-split regressed (101us); R8/R11 ~90us is the igd plateau —
// 11 structural variants (delivery/ILP/VALU/TLP/barriers) all null; per-step overhead (~330cyc:
// MFMA->acc latency + moves + waitcnt) resists source scheduling. R15 consolidates the rest:
// pack's manual e4m3 emulation (~300 VALU ops/thread) -> v_cvt_pk_fp8_f32 / v_cvt_pk_f32_fp8
// (~40 ops/thread). igd_main and reduce are byte-identical to R11.
// Harness poison fill of ws (~42 us @6.5TB/s) is a fixed floor inside the timed window.

typedef float f32x16 __attribute__((ext_vector_type(16)));
typedef float f32x2 __attribute__((ext_vector_type(2)));
typedef int i32x8 __attribute__((ext_vector_type(8)));
typedef unsigned long long u64;

#define DIM 64
#define NSPLIT 12
#define UNITB 2048            // bytes per 32-col unit: 4 qfrags x 64 lanes x 8 B
#define CHUNKU 8              // units per LDS chunk
#define CHUNKB (CHUNKU * UNITB)   // 16 KB
#define MTILE 256             // rows per block (4 waves x 64 rows)

union BFrag { u64 q[4]; i32x8 v; };

// async global->LDS DMA, 16 B/lane (global_load_lds_dwordx4) and 4 B/lane
__device__ __forceinline__ void g2lds16(const void* g, void* l) {
    __builtin_amdgcn_global_load_lds(
        (const __attribute__((address_space(1))) unsigned int*)g,
        (__attribute__((address_space(3))) unsigned int*)l, 16, 0, 0);
}
__device__ __forceinline__ void g2lds4(const void* g, void* l) {
    __builtin_amdgcn_global_load_lds(
        (const __attribute__((address_space(1))) unsigned int*)g,
        (__attribute__((address_space(3))) unsigned int*)l, 4, 0, 0);
}

// ---------------- pack (HW fp8 converters) ----------------
// encode16: 16 fp32 (optionally pre-scaled) -> 2 u64 of e4m3 bytes + exact fp32 sum of squares
// of the DECODED values (consistency: d2 is then an exact distance between rounded points).
__device__ __forceinline__ void encode16(const float* f, u64 w[2], float& sumsq) {
    unsigned int w32[4];
#pragma unroll
    for (int k = 0; k < 4; ++k) {
        int lo = __builtin_amdgcn_cvt_pk_fp8_f32(f[4 * k],     f[4 * k + 1], 0,  false);
        w32[k] = __builtin_amdgcn_cvt_pk_fp8_f32(f[4 * k + 2], f[4 * k + 3], lo, true);
    }
#pragma unroll
    for (int k = 0; k < 4; ++k) {
        f32x2 d0 = __builtin_amdgcn_cvt_pk_f32_fp8(w32[k], false);
        f32x2 d1 = __builtin_amdgcn_cvt_pk_f32_fp8(w32[k], true);
        sumsq += d0.x * d0.x + d0.y * d0.y + d1.x * d1.x + d1.y * d1.y;
    }
    w[0] = (u64)w32[0] | ((u64)w32[1] << 32);
    w[1] = (u64)w32[2] | ((u64)w32[3] << 32);
}

// Bp layout (32x32x64 B-operand): lane L = h*32 + c31 holds col = u*32+c31, k = h*32 + 0..31:
//   Bp[u*2048 + q*512 + L*8 + b] = e4m3(x[col][h*32 + q*8 + b]).
// xsq[col] = exact fp32 sum of squares of decoded values.
// pf -> Ab row-major fp8(-2*pf) (A-operand = contiguous 32 B per lane); pfsq = 0.25*sum(dec^2).
__global__ void pack_kernel(const float* __restrict__ x, const float* __restrict__ pf,
                            unsigned char* __restrict__ Bp, unsigned char* __restrict__ Ab,
                            float* __restrict__ xsq, float* __restrict__ pfsq,
                            float* __restrict__ out, int N, int M) {
    int gid = blockIdx.x * blockDim.x + threadIdx.x;
    if (gid == 0) out[0] = 0.f;
    if (gid < N * 4) {
        int col = gid >> 2, t = gid & 3;
        const float* s = x + (size_t)col * DIM + t * 16;
        float4 v0 = *(const float4*)(s);
        float4 v1 = *(const float4*)(s + 4);
        float4 v2 = *(const float4*)(s + 8);
        float4 v3 = *(const float4*)(s + 12);
        float f[16] = {v0.x, v0.y, v0.z, v0.w, v1.x, v1.y, v1.z, v1.w,
                       v2.x, v2.y, v2.z, v2.w, v3.x, v3.y, v3.z, v3.w};
        float partial = 0.f;
        u64 w[2];
        encode16(f, w, partial);
        int u = col >> 5, c31 = col & 31;
        unsigned char* ub = Bp + (size_t)u * UNITB;
        int h = t >> 1;
#pragma unroll
        for (int ss = 0; ss < 2; ++ss) {
            int q = (t & 1) * 2 + ss;
            *(u64*)(ub + (size_t)q * 512 + (size_t)(h * 32 + c31) * 8) = w[ss];
        }
        partial += __shfl_xor(partial, 1);
        partial += __shfl_xor(partial, 2);
        if (t == 0) xsq[col] = partial;
    } else {
        int g = gid - N * 4;
        int row = g >> 2, q = g & 3;
        if (row >= M) return;
        const float* s = pf + (size_t)row * DIM + q * 16;
        float4 v0 = *(const float4*)(s);
        float4 v1 = *(const float4*)(s + 4);
        float4 v2 = *(const float4*)(s + 8);
        float4 v3 = *(const float4*)(s + 12);
        float f[16] = {v0.x, v0.y, v0.z, v0.w, v1.x, v1.y, v1.z, v1.w,
                       v2.x, v2.y, v2.z, v2.w, v3.x, v3.y, v3.z, v3.w};
#pragma unroll
        for (int j = 0; j < 16; ++j) f[j] *= -2.f;
        float partial = 0.f;
        u64 w[2];
        encode16(f, w, partial);
        *(u64*)(Ab + (size_t)row * DIM + q * 16)     = w[0];
        *(u64*)(Ab + (size_t)row * DIM + q * 16 + 8) = w[1];
        partial += __shfl_xor(partial, 1);
        partial += __shfl_xor(partial, 2);
        if (q == 0) pfsq[row] = partial * 0.25f;
    }
}

// ---------------- main: async-LDS dbuf, K=64 fp8 GEMM + row-min (byte-identical to R11) ------
__global__ __launch_bounds__(256, 3)
void igd_main(const unsigned char* __restrict__ A, const unsigned char* __restrict__ Bp,
              const float* __restrict__ xsq, float* __restrict__ partial, int N) {
    __shared__ unsigned char ldsB[2][CHUNKB];     // 32 KB
    __shared__ float ldsX[2][CHUNKU * 32];        // 2 KB
    const int tid = threadIdx.x;
    const int mTile  = blockIdx.x;
    const int nsplit = blockIdx.y;
    const int lane = tid & 63;
    const int wave = tid >> 6;
    const int half = lane >> 5;
    const int l31  = lane & 31;
    const int rowBase = mTile * MTILE + wave * 64;

    // ragged split over 32-col units: splits 0..7 get 43, 8..11 get 42
    const int utotal = N / 32;
    const int ubase  = utotal / NSPLIT;
    const int urem   = utotal % NSPLIT;
    const int ustart = nsplit * ubase + (nsplit < urem ? nsplit : urem);
    const int ucount = ubase + (nsplit < urem ? 1 : 0);
    const int nch = (ucount + CHUNKU - 1) / CHUNKU;

    // Persistent A operands: lane holds A[row = l31 + 32g][k = half*32 .. +31] (32 B contiguous)
    BFrag a[2];
#pragma unroll
    for (int g = 0; g < 2; ++g) {
        const unsigned char* ap = A + (size_t)(rowBase + 32 * g + l31) * DIM + half * 32;
#pragma unroll
        for (int qq = 0; qq < 4; ++qq)
            a[g].q[qq] = *(const u64*)(ap + qq * 8);
    }

    const unsigned char* gB = Bp + (size_t)ustart * UNITB;
    const float* gX = xsq + ustart * 32;

    // Async cooperative stage: direct global->LDS DMA, no VGPR round-trip, no mid-chunk wait.
#define STAGE(c, buf)                                                          \
    {                                                                          \
        int bytes = (ucount - (c) * CHUNKU) < CHUNKU ? (ucount - (c) * CHUNKU) * UNITB : CHUNKB; \
        const unsigned char* src = gB + (size_t)(c) * CHUNKB;                  \
        _Pragma("unroll")                                                      \
        for (int i = 0; i < 4; ++i) {                                          \
            int off = i * 4096 + tid * 16;                                     \
            if (off < bytes)                                                   \
                g2lds16(src + off, &ldsB[buf][off]);                           \
        }                                                                      \
        int xcnt = bytes >> 6;                                                 \
        if (tid < xcnt)                                                        \
            g2lds4(gX + (c) * (CHUNKU * 32) + tid, &ldsX[buf][tid]);           \
    }

    f32x16 zero, m0, m1;
#pragma unroll
    for (int r = 0; r < 16; ++r) { zero[r] = 0.f; m0[r] = 1e30f; m1[r] = 1e30f; }

#define LOADF(rr, lb, u)                                                       \
    {                                                                          \
        const unsigned char* p = (lb) + (u) * UNITB;                           \
        rr.q[0] = *(const u64*)(p);                                            \
        rr.q[1] = *(const u64*)(p + 512);                                      \
        rr.q[2] = *(const u64*)(p + 1024);                                     \
        rr.q[3] = *(const u64*)(p + 1536);                                     \
    }

    // Unity E8M0 scales (0x7F = 2^0): bit-identical to non-scaled fp8 accumulation.
#define MFMA2(accA, accB, bfrag)                                               \
    {                                                                          \
        accA = __builtin_amdgcn_mfma_scale_f32_32x32x64_f8f6f4(                \
            a[0].v, bfrag.v, zero, 0, 0, 0, 0x7F7F7F7F, 0, 0x7F7F7F7F);        \
        accB = __builtin_amdgcn_mfma_scale_f32_32x32x64_f8f6f4(                \
            a[1].v, bfrag.v, zero, 0, 0, 0, 0x7F7F7F7F, 0, 0x7F7F7F7F);        \
    }

#define MINS(accA, accB, xq)                                                   \
    {                                                                          \
        _Pragma("unroll")                                                      \
        for (int r = 0; r < 16; ++r) {                                         \
            m0[r] = fminf(m0[r], accA[r] + (xq));                              \
            m1[r] = fminf(m1[r], accB[r] + (xq));                              \
        }                                                                      \
    }

    STAGE(0, 0);
    __syncthreads();   // drains the async loads (vmcnt) + barrier

    for (int c = 0; c < nch; ++c) {
        const int buf = c & 1;
        if (c + 1 < nch) STAGE(c + 1, buf ^ 1);   // async; drains only at the next barrier
        const int cnt = (ucount - c * CHUNKU) < CHUNKU ? (ucount - c * CHUNKU) : CHUNKU;
        const unsigned char* lb = &ldsB[buf][0] + lane * 8;
        const float* lx = &ldsX[buf][0] + l31;
        if (cnt == CHUNKU) {
            BFrag b0, b1;
            LOADF(b0, lb, 0);
#pragma unroll
            for (int u = 0; u < CHUNKU; u += 2) {
                LOADF(b1, lb, u + 1);
                f32x16 acA0, acA1;
                MFMA2(acA0, acA1, b0);
                MINS(acA0, acA1, lx[u * 32]);
                if (u + 2 < CHUNKU) LOADF(b0, lb, u + 2);
                f32x16 acB0, acB1;
                MFMA2(acB0, acB1, b1);
                MINS(acB0, acB1, lx[(u + 1) * 32]);
            }
        } else {
            BFrag bt;
            for (int u = 0; u < cnt; ++u) {       // tail chunk: 2 or 3 units
                LOADF(bt, lb, u);
                f32x16 t0, t1;
                MFMA2(t0, t1, bt);
                MINS(t0, t1, lx[u * 32]);
            }
        }
        __syncthreads();
    }
#undef STAGE
#undef LOADF
#undef MFMA2
#undef MINS

    // cross-lane min over the 32 lanes sharing a row
#pragma unroll
    for (int mask = 1; mask <= 16; mask <<= 1) {
#pragma unroll
        for (int r = 0; r < 16; ++r) {
            m0[r] = fminf(m0[r], __shfl_xor(m0[r], mask));
            m1[r] = fminf(m1[r], __shfl_xor(m1[r], mask));
        }
    }
    if (l31 == 0) {
        // C/D layout (shape-determined, FMT-independent): row = (r&3)+8*(r>>2)+4*half
#pragma unroll
        for (int r = 0; r < 16; ++r) {
            int row0 = rowBase + (r & 3) + 8 * (r >> 2) + 4 * half;
            partial[(size_t)row0 * NSPLIT + nsplit] = m0[r];
            partial[(size_t)(row0 + 32) * NSPLIT + nsplit] = m1[r];
        }
    }
}

// ---------------- reduce: min over splits, add pfsq, sqrt, mean ----------------
__global__ void reduce_kernel(const float* __restrict__ partial, const float* __restrict__ pfsq,
                              float* __restrict__ out, int M, float invM) {
    int row = blockIdx.x * blockDim.x + threadIdx.x;
    float v = 0.f;
    if (row < M) {
        const float* p = partial + (size_t)row * NSPLIT;
        float mn = 3.4e38f;
#pragma unroll
        for (int s = 0; s < NSPLIT; ++s) mn = fminf(mn, p[s]);
        float d2 = mn + pfsq[row];
        v = sqrtf(fmaxf(d2, 0.f)) * invM;
    }
#pragma unroll
    for (int m = 1; m < 64; m <<= 1) v += __shfl_xor(v, m);
    __shared__ float wsum[4];
    int lane = threadIdx.x & 63, w = threadIdx.x >> 6;
    if (lane == 0) wsum[w] = v;
    __syncthreads();
    if (threadIdx.x == 0) atomicAdd(out, wsum[0] + wsum[1] + wsum[2] + wsum[3]);
}

extern "C" void kernel_launch(void* const* d_in, const int* in_sizes, int n_in,
                              void* d_out, int out_size, void* d_ws, size_t ws_size,
                              hipStream_t stream) {
    const float* x  = (const float*)d_in[0];   // [N, 64]
    const float* pf = (const float*)d_in[1];   // [M, 64]
    const int N = in_sizes[0] / DIM;
    const int M = in_sizes[1] / DIM;

    char* ws = (char*)d_ws;
    unsigned char* Bp = (unsigned char*)ws;                        // N*64 bytes (packed fp8)
    unsigned char* Ab = (unsigned char*)(ws + (size_t)N * DIM);    // M*64 bytes
    float* xsq  = (float*)(ws + (size_t)(N + M) * DIM);            // N floats
    float* pfsq = xsq + N;                                         // M floats
    float* part = pfsq + M;                                        // M*NSPLIT floats

    int packThreads = (N + M) * 4;
    pack_kernel<<<dim3((packThreads + 255) / 256), 256, 0, stream>>>(
        x, pf, Bp, Ab, xsq, pfsq, (float*)d_out, N, M);
    igd_main<<<dim3(M / MTILE, NSPLIT), 256, 0, stream>>>(Ab, Bp, xsq, part, N);
    reduce_kernel<<<dim3((M + 255) / 256), 256, 0, stream>>>(part, pfsq, (float*)d_out, M, 1.f / (float)M);
}